// Round 16
// baseline (2423.487 us; speedup 1.0000x reference)
//
#include <hip/hip_runtime.h>

// Problem constants
#define B_ 32
#define S_ 2048
#define DA 32
#define DH 128
#define DS 64
#define DS2 4096

typedef _Float16 half8 __attribute__((ext_vector_type(8)));
typedef _Float16 half4v __attribute__((ext_vector_type(4)));
typedef float f32x4 __attribute__((ext_vector_type(4)));

template <int CTRL>
__device__ __forceinline__ float dpp_add(float x) {
  int t = __builtin_amdgcn_update_dpp(0, __float_as_int(x), CTRL, 0xF, 0xF, true);
  return x + __int_as_float(t);
}
__device__ __forceinline__ float row_sum16(float x) {
  x = dpp_add<0xB1>(x);
  x = dpp_add<0x4E>(x);
  x = dpp_add<0x141>(x);
  x = dpp_add<0x140>(x);
  return x;
}

// async global->LDS DMA, 16 B per lane (dest = wave-uniform base + lane*16)
__device__ __forceinline__ void gl2lds16(const void* g, void* l) {
  __builtin_amdgcn_global_load_lds(
      (const __attribute__((address_space(1))) void*)g,
      (__attribute__((address_space(3))) void*)l, 16, 0, 0);
}

// ---------------------------------------------------------------------------
// fp8 e4m3(fn) encode/decode for the T residual plane (R14/R15-validated:
// absmax 0.0039 vs threshold 0.0148). Residual r = v - fp16(v) stored as
// e4m3(r*2048) -> total T error ~2^-15 |v|.
// ---------------------------------------------------------------------------
__device__ __forceinline__ unsigned f32_to_e4m3(float x) {
  unsigned u = __float_as_uint(x);
  unsigned s = (u >> 24) & 0x80u;
  float ax = fabsf(x);
  if (ax >= 448.f) return s | 0x7Eu;          // saturate (no inf in fn)
  if (ax < 0x1p-6f) {                          // subnormal: m = round(ax*512)
    int m = (int)rintf(ax * 512.f);            // 0..8 (8 == 2^-6 normal, ok)
    return s | (unsigned)m;
  }
  unsigned au = __float_as_uint(ax);
  au += 0x7FFFFu + ((au >> 20) & 1u);          // RNE at 3 mantissa bits
  int e = (int)((au >> 23) & 0xffu) - 120;     // e4m3 exponent
  if (e >= 16) return s | 0x7Eu;
  unsigned m = (au >> 20) & 7u;
  return s | ((unsigned)e << 3) | m;
}

__device__ __forceinline__ float e4m3_to_f32(unsigned b) {
  unsigned e = (b >> 3) & 15u, m = b & 7u;
  float vn = __uint_as_float(((e + 120u) << 23) | (m << 20));
  float vs = (float)(int)m * 0x1p-9f;
  float mag = e ? vn : vs;
  return (b & 0x80u) ? -mag : mag;
}

// ---------------------------------------------------------------------------
// RNN: producers double-buffer their private staging (T4 counted-vmcnt):
// iteration s issues DMA(s) into buf A, vmcnt(12) waits only for DMA(s-3)
// (buf B), decodes s-3 into the f32 ring, publishes flag. Loads for s stay
// in flight under the decode -- R15's vmcnt(0)-per-step drain (the 3x
// regression) is gone. Ring shrunk to 4 slots to fit LDS (64+72 KB).
// ---------------------------------------------------------------------------
struct SharedRnn {
  float ring[4][4096];           // 64 KB decoded f32 T
  _Float16 stgh[3][2][4096];     // 48 KB per-producer double-buffered hi
  unsigned char stgl[3][2][4096];// 24 KB per-producer double-buffered lo
  int flags[4];
  int cons;
};
struct SharedGemm {
  _Float16 Ah[128 * 128];   // 32 KB; epilogue scratch (fp16 plane, XOR-swz)
  _Float16 Al[128 * 128];   // 32 KB; epilogue scratch (byte plane, XOR-swz)
  _Float16 Bh[128 * 128];   // 32 KB  [nloc*128 + (k ^ ((n&7)<<3))]
  _Float16 Bl[128 * 128];
};
struct SharedMlp {
  float a_t[DA][64];        // 8 KB
  float w0_l[DA][DH];       // 16 KB
  float h0t[DH][64];        // 32 KB
};
union SharedU {
  SharedRnn r;
  SharedGemm g;
  SharedMlp m;
};

// ---------------------------------------------------------------------------
// w2 split precompute (once): w2 [k][n] fp32 -> w2h/w2l [n][k^swz] fp16,
// lo scaled by 2^11 so it stays in fp16 normal range.
// ---------------------------------------------------------------------------
__global__ __launch_bounds__(256) void k_split(
    const float* __restrict__ w2, _Float16* __restrict__ w2h,
    _Float16* __restrict__ w2l)
{
  for (int e = blockIdx.x * 256 + threadIdx.x; e < DH * DS2;
       e += gridDim.x * 256) {
    int n = e >> 7, k = e & 127;
    float v = w2[(size_t)k * DS2 + n];
    _Float16 hi = (_Float16)v;
    _Float16 lo = (_Float16)((v - (float)hi) * 2048.0f);
    int kk = k ^ ((n & 7) << 3);
    w2h[(size_t)n * DH + kk] = hi;
    w2l[(size_t)n * DH + kk] = lo;
  }
}

// ---------------------------------------------------------------------------
// MLP tile (R0-validated 256-thread compute): 64 tokens; epilogue emits the
// fp16 hi/lo split of h1 in [m][k^swz] layout (k = feature).
// ---------------------------------------------------------------------------
__device__ __forceinline__ void mlp_tile(
    const float* __restrict__ actions, const float* __restrict__ w0,
    const float* __restrict__ b0, const float* __restrict__ w1,
    const float* __restrict__ b1, _Float16* __restrict__ h1h,
    _Float16* __restrict__ h1l, int s_base, int m0, SharedMlp& sm, int tid)
{
#pragma unroll
  for (int q = 0; q < 2; ++q) {
    int g = tid + 256 * q;
    int tok = g >> 3, kq = g & 7;
    int tl = m0 + tok;
    int b = tl & 31, s = s_base + (tl >> 5);
    float4 v = *(const float4*)(actions + ((size_t)b * S_ + s) * DA + 4 * kq);
    sm.a_t[4 * kq + 0][tok] = v.x; sm.a_t[4 * kq + 1][tok] = v.y;
    sm.a_t[4 * kq + 2][tok] = v.z; sm.a_t[4 * kq + 3][tok] = v.w;
  }
#pragma unroll
  for (int q = 0; q < 4; ++q) {
    int g = tid + 256 * q;
    ((float4*)&sm.w0_l[0][0])[g] = ((const float4*)w0)[g];
  }
  __syncthreads();

  const int tm = tid & 15;
  const int tn = tid >> 4;

  float acc[4][8];
#pragma unroll
  for (int mi = 0; mi < 4; ++mi)
#pragma unroll
    for (int ni = 0; ni < 8; ++ni) acc[mi][ni] = 0.f;

#pragma unroll 4
  for (int k = 0; k < DA; ++k) {
    float4 a4 = *(const float4*)&sm.a_t[k][4 * tm];
    float4 wa = *(const float4*)&sm.w0_l[k][8 * tn];
    float4 wb = *(const float4*)&sm.w0_l[k][8 * tn + 4];
    float av[4] = {a4.x, a4.y, a4.z, a4.w};
    float wv[8] = {wa.x, wa.y, wa.z, wa.w, wb.x, wb.y, wb.z, wb.w};
#pragma unroll
    for (int mi = 0; mi < 4; ++mi)
#pragma unroll
      for (int ni = 0; ni < 8; ++ni) acc[mi][ni] += av[mi] * wv[ni];
  }
  {
    float4 ba = *(const float4*)(b0 + 8 * tn);
    float4 bb = *(const float4*)(b0 + 8 * tn + 4);
    float bv[8] = {ba.x, ba.y, ba.z, ba.w, bb.x, bb.y, bb.z, bb.w};
#pragma unroll
    for (int mi = 0; mi < 4; ++mi)
#pragma unroll
      for (int ni = 0; ni < 8; ++ni)
        sm.h0t[8 * tn + ni][4 * tm + mi] = fmaxf(acc[mi][ni] + bv[ni], 0.f);
  }
  __syncthreads();

  float acc1[4][8];
#pragma unroll
  for (int mi = 0; mi < 4; ++mi)
#pragma unroll
    for (int ni = 0; ni < 8; ++ni) acc1[mi][ni] = 0.f;

#pragma unroll 4
  for (int k = 0; k < DH; ++k) {
    float4 h4 = *(const float4*)&sm.h0t[k][4 * tm];
    float4 wa = *(const float4*)(w1 + (size_t)k * DH + 8 * tn);
    float4 wb = *(const float4*)(w1 + (size_t)k * DH + 8 * tn + 4);
    float av[4] = {h4.x, h4.y, h4.z, h4.w};
    float wv[8] = {wa.x, wa.y, wa.z, wa.w, wb.x, wb.y, wb.z, wb.w};
#pragma unroll
    for (int mi = 0; mi < 4; ++mi)
#pragma unroll
      for (int ni = 0; ni < 8; ++ni) acc1[mi][ni] += av[mi] * wv[ni];
  }
  {
    float4 ba = *(const float4*)(b1 + 8 * tn);
    float4 bb = *(const float4*)(b1 + 8 * tn + 4);
    float bv[8] = {ba.x, ba.y, ba.z, ba.w, bb.x, bb.y, bb.z, bb.w};
#pragma unroll
    for (int mi = 0; mi < 4; ++mi) {
      const int m = m0 + 4 * tm + mi;
      half8 hv, lv;
#pragma unroll
      for (int ni = 0; ni < 8; ++ni) {
        float h = fmaxf(acc1[mi][ni] + bv[ni], 0.f);
        _Float16 hi = (_Float16)h;
        hv[ni] = hi;
        lv[ni] = (_Float16)((h - (float)hi) * 2048.0f);
      }
      const int off = m * DH + ((8 * tn) ^ ((m & 7) << 3));
      *(half8*)(h1h + off) = hv;
      *(half8*)(h1l + off) = lv;
    }
  }
}

// ---------------------------------------------------------------------------
// MFMA trans GEMM (R10-validated math): block owns n-strip; Bh/Bl pinned;
// per m-tile: stage Ah/Al -> MFMA -> epilogue through XOR-swizzled LDS
// scratch (kills R15's 4-way write conflicts) -> 16-byte coalesced stores.
// C/D: col = lane&15, row = (lane>>4)*4 + reg (guide m89/m91 verified).
// ---------------------------------------------------------------------------
__device__ __forceinline__ void trans_loop(
    const _Float16* __restrict__ h1h, const _Float16* __restrict__ h1l,
    const _Float16* __restrict__ w2h, const _Float16* __restrict__ w2l,
    const float* __restrict__ b2, _Float16* __restrict__ transh,
    unsigned char* __restrict__ translo,
    int MT, int x, SharedGemm& sg, int tid)
{
  const int w  = tid >> 6;
  const int lw = tid & 63;
  const int strip = x / 7;            // 0..31
  const int idx   = x % 7;
  const int n0 = strip * 128;

  // per-wave linear 8 KB staging helper (32 KB array / 4 waves)
  auto stage32k = [&](const _Float16* src, _Float16* dst) {
    const _Float16* s = src + w * 4096 + lw * 8;
    _Float16* d = dst + w * 4096;
#pragma unroll
    for (int i = 0; i < 8; ++i)
      gl2lds16(s + i * 512, d + i * 512);
  };

  // pin B strip (w2 splits are [n][k^swz], contiguous per strip)
  stage32k(w2h + (size_t)n0 * DH, sg.Bh);
  stage32k(w2l + (size_t)n0 * DH, sg.Bl);

  const int fr = lw & 15;             // frag row/col index
  const int kg = lw >> 4;             // 0..3 k-group
  const int wr = w >> 1, wc = w & 1;  // wave quadrant

  float b2v[4];
#pragma unroll
  for (int fn = 0; fn < 4; ++fn)
    b2v[fn] = b2[n0 + wc * 64 + fn * 16 + fr];

  const f32x4 fz = {0.f, 0.f, 0.f, 0.f};

  for (int mt = idx; mt < MT; mt += 7) {
    const int m0 = mt * 128;
    stage32k(h1h + (size_t)m0 * DH, sg.Ah);
    stage32k(h1l + (size_t)m0 * DH, sg.Al);
    asm volatile("s_waitcnt vmcnt(0)" ::: "memory");
    __syncthreads();

    f32x4 ahh[4][4], axx[4][4], all_[4][4];
#pragma unroll
    for (int fm = 0; fm < 4; ++fm)
#pragma unroll
      for (int fn = 0; fn < 4; ++fn) {
        ahh[fm][fn] = fz;
        axx[fm][fn] = fz;
        all_[fm][fn] = fz;
      }

#pragma unroll
    for (int kc = 0; kc < 4; ++kc) {
      const int k0 = kc * 32 + kg * 8;
      half8 bh[4], bl[4];
#pragma unroll
      for (int fn = 0; fn < 4; ++fn) {
        const int n = wc * 64 + fn * 16 + fr;
        const int off = n * DH + (k0 ^ ((n & 7) << 3));
        bh[fn] = *(const half8*)&sg.Bh[off];
        bl[fn] = *(const half8*)&sg.Bl[off];
      }
#pragma unroll
      for (int fm = 0; fm < 4; ++fm) {
        const int m = wr * 64 + fm * 16 + fr;
        const int off = m * DH + (k0 ^ ((m & 7) << 3));
        half8 ah = *(const half8*)&sg.Ah[off];
        half8 al = *(const half8*)&sg.Al[off];
#pragma unroll
        for (int fn = 0; fn < 4; ++fn) {
          ahh[fm][fn] = __builtin_amdgcn_mfma_f32_16x16x32_f16(
              ah, bh[fn], ahh[fm][fn], 0, 0, 0);
          axx[fm][fn] = __builtin_amdgcn_mfma_f32_16x16x32_f16(
              ah, bl[fn], axx[fm][fn], 0, 0, 0);
          axx[fm][fn] = __builtin_amdgcn_mfma_f32_16x16x32_f16(
              al, bh[fn], axx[fm][fn], 0, 0, 0);
          all_[fm][fn] = __builtin_amdgcn_mfma_f32_16x16x32_f16(
              al, bl[fn], all_[fm][fn], 0, 0, 0);
        }
      }
    }
    __syncthreads();   // all Ah/Al reads done -> reuse as epilogue scratch

    // scatter into XOR-swizzled LDS scratch (conflict-free across kg rows)
    _Float16* sch = sg.Ah;                      // [128][128] fp16
    unsigned char* scl = (unsigned char*)sg.Al; // [128][128] u8
#pragma unroll
    for (int fm = 0; fm < 4; ++fm)
#pragma unroll
      for (int fn = 0; fn < 4; ++fn) {
        const int cloc = wc * 64 + fn * 16 + fr;
#pragma unroll
        for (int r = 0; r < 4; ++r) {
          const int rloc = wr * 64 + fm * 16 + kg * 4 + r;
          float v = ahh[fm][fn][r] + axx[fm][fn][r] * (1.0f / 2048.0f) +
                    all_[fm][fn][r] * (1.0f / 4194304.0f) + b2v[fn];
          _Float16 hi = (_Float16)v;
          sch[rloc * 128 + (cloc ^ ((rloc & 7) << 3))] = hi;
          scl[rloc * 128 + (cloc ^ ((rloc & 7) << 4))] =
              (unsigned char)f32_to_e4m3((v - (float)hi) * 2048.0f);
        }
      }
    __syncthreads();

    // coalesced 16-byte copy-out (same XOR per 8/16-element group)
#pragma unroll
    for (int it = 0; it < 8; ++it) {           // hi: 2048 x 16B chunks
      const int cch = tid + it * 256;
      const int row = cch >> 4, seg = cch & 15;
      half8 vv = *(const half8*)&sch[row * 128 + ((seg * 8) ^ ((row & 7) << 3))];
      *(half8*)(transh + (size_t)(m0 + row) * DS2 + n0 + seg * 8) = vv;
    }
#pragma unroll
    for (int it = 0; it < 4; ++it) {           // lo: 1024 x 16B chunks
      const int ccl = tid + it * 256;
      const int row = ccl >> 3, seg = ccl & 7;
      uint4 vv = *(const uint4*)&scl[row * 128 + ((seg * 16) ^ ((row & 7) << 4))];
      *(uint4*)(translo + (size_t)(m0 + row) * DS2 + n0 + seg * 16) = vv;
    }
    __syncthreads();   // scratch reads done before next tile's staging DMA
  }
}

// ---------------------------------------------------------------------------
// Standalone MLP kernel (chunk 0 priming)
// ---------------------------------------------------------------------------
__global__ __launch_bounds__(256) void k_mlp01(
    const float* __restrict__ actions, const float* __restrict__ w0,
    const float* __restrict__ b0, const float* __restrict__ w1,
    const float* __restrict__ b1, _Float16* __restrict__ h1h,
    _Float16* __restrict__ h1l, int s_base)
{
  __shared__ SharedMlp sm;
  mlp_tile(actions, w0, b0, w1, b1, h1h, h1l, s_base, blockIdx.x * 64, sm,
           threadIdx.x);
}

// ---------------------------------------------------------------------------
// Combined pipelined kernel, launch index c = 0..nch, grid 256 x 256 thr:
//  blocks 0..31  : rnn for chunk c-1 (if c>0) -- producers double-buffer
//                  staging with counted vmcnt(12) (loads for s in flight
//                  under decode of s-3); consumer = R12-validated f32 path.
//  blocks 32..255: MFMA trans tiles for chunk c (if c<nch), then mlp c+1.
// ---------------------------------------------------------------------------
__global__ __launch_bounds__(256, 1) void k_comb(
    const float* __restrict__ actions, const float* __restrict__ w0,
    const float* __restrict__ b0, const float* __restrict__ w1,
    const float* __restrict__ b1, const _Float16* __restrict__ w2h,
    const _Float16* __restrict__ w2l, const float* __restrict__ b2,
    const float* __restrict__ init_hidden,
    _Float16* __restrict__ transh0, _Float16* __restrict__ transh1,
    unsigned char* __restrict__ translo0, unsigned char* __restrict__ translo1,
    _Float16* __restrict__ h1h0, _Float16* __restrict__ h1l0,
    _Float16* __restrict__ h1h1, _Float16* __restrict__ h1l1,
    float* __restrict__ hstate, float* __restrict__ out,
    int c, int SC, int nch)
{
  __shared__ SharedU sh;
  const int tid = threadIdx.x;
  const int M = SC * 32;

  if (blockIdx.x >= 32) {
    // -------------------- GEMM blocks (224) --------------------
    const int x = blockIdx.x - 32;
    if (c < nch) {
      const _Float16* h1h = (c & 1) ? h1h1 : h1h0;
      const _Float16* h1l = (c & 1) ? h1l1 : h1l0;
      _Float16* transh = (c & 1) ? transh1 : transh0;
      unsigned char* translo = (c & 1) ? translo1 : translo0;
      trans_loop(h1h, h1l, w2h, w2l, b2, transh, translo, M / 128, x, sh.g,
                 tid);
      if (c + 1 < nch) {
        __syncthreads();
        _Float16* hh = ((c + 1) & 1) ? h1h1 : h1h0;
        _Float16* hl = ((c + 1) & 1) ? h1l1 : h1l0;
        for (int j = x; j < M / 64; j += 224) {
          mlp_tile(actions, w0, b0, w1, b1, hh, hl, (c + 1) * SC, j * 64,
                   sh.m, tid);
          __syncthreads();
        }
      }
    }
    return;
  }

  // -------------------- RNN blocks (chunk c-1) ----------------------------
  if (c == 0) return;
  const int cc = c - 1;               // rnn chunk index
  const _Float16* transh = (cc & 1) ? transh1 : transh0;
  const unsigned char* translo = (cc & 1) ? translo1 : translo0;
  const int s_base = cc * SC;
  const int wv = tid >> 6;            // 0..3
  const int lane = tid & 63;
  const int b = blockIdx.x;

  if (tid < 4) sh.r.flags[tid] = 0;
  if (tid == 4) sh.r.cons = 0;
  __syncthreads();

  const _Float16* baseh = transh + (size_t)b * DS2;
  const unsigned char* basel = translo + (size_t)b * DS2;

  if (wv > 0) {
    // producer p: steps s ≡ p (mod 3); double-buffered staging, counted
    // vmcnt. Iter s: issue DMA(s)->buf[bs]; vmcnt(12) (drains DMA(s-3),
    // leaves DMA(s) in flight); gate ring slot; decode s-3; publish flag.
    const int p = wv - 1;
    int pend = -1, bs = 0;
    for (int s = p; s < SC; s += 3) {
      const _Float16* gh = baseh + (size_t)s * (32 * DS2) + 8 * lane;
      _Float16* sth = &sh.r.stgh[p][bs][0];
#pragma unroll
      for (int q = 0; q < 8; ++q)
        gl2lds16(gh + q * 512, sth + q * 512);
      const unsigned char* gl = basel + (size_t)s * (32 * DS2) + 16 * lane;
      unsigned char* stl = &sh.r.stgl[p][bs][0];
#pragma unroll
      for (int q = 0; q < 4; ++q)
        gl2lds16(gl + q * 1024, stl + q * 1024);

      if (pend >= 0) {
        asm volatile("s_waitcnt vmcnt(12)" ::: "memory");   // pend's loads done
        while (pend - __hip_atomic_load(&sh.r.cons, __ATOMIC_RELAXED,
                                        __HIP_MEMORY_SCOPE_WORKGROUP) > 3)
          __builtin_amdgcn_s_sleep(2);                      // ring slot free
        const _Float16* dh = &sh.r.stgh[p][bs ^ 1][0];
        const unsigned char* dl = &sh.r.stgl[p][bs ^ 1][0];
        float* rg = &sh.r.ring[pend & 3][0];
#pragma unroll 4
        for (int i = 0; i < 16; ++i) {
          const int eb = (i * 64 + lane) * 4;
          half4v h4 = *(const half4v*)&dh[eb];
          unsigned l4 = *(const unsigned*)&dl[eb];
          float4 o;
          o.x = fmaf(e4m3_to_f32(l4 & 0xffu), (1.0f / 2048.0f), (float)h4[0]);
          o.y = fmaf(e4m3_to_f32((l4 >> 8) & 0xffu), (1.0f / 2048.0f), (float)h4[1]);
          o.z = fmaf(e4m3_to_f32((l4 >> 16) & 0xffu), (1.0f / 2048.0f), (float)h4[2]);
          o.w = fmaf(e4m3_to_f32(l4 >> 24), (1.0f / 2048.0f), (float)h4[3]);
          *(float4*)&rg[eb] = o;
        }
        __hip_atomic_store(&sh.r.flags[pend & 3], pend + 1, __ATOMIC_RELEASE,
                           __HIP_MEMORY_SCOPE_WORKGROUP);
      }
      pend = s; bs ^= 1;
    }
    if (pend >= 0) {   // tail: decode last staged step
      asm volatile("s_waitcnt vmcnt(0)" ::: "memory");
      while (pend - __hip_atomic_load(&sh.r.cons, __ATOMIC_RELAXED,
                                      __HIP_MEMORY_SCOPE_WORKGROUP) > 3)
        __builtin_amdgcn_s_sleep(2);
      const _Float16* dh = &sh.r.stgh[p][bs ^ 1][0];
      const unsigned char* dl = &sh.r.stgl[p][bs ^ 1][0];
      float* rg = &sh.r.ring[pend & 3][0];
#pragma unroll 4
      for (int i = 0; i < 16; ++i) {
        const int eb = (i * 64 + lane) * 4;
        half4v h4 = *(const half4v*)&dh[eb];
        unsigned l4 = *(const unsigned*)&dl[eb];
        float4 o;
        o.x = fmaf(e4m3_to_f32(l4 & 0xffu), (1.0f / 2048.0f), (float)h4[0]);
        o.y = fmaf(e4m3_to_f32((l4 >> 8) & 0xffu), (1.0f / 2048.0f), (float)h4[1]);
        o.z = fmaf(e4m3_to_f32((l4 >> 16) & 0xffu), (1.0f / 2048.0f), (float)h4[2]);
        o.w = fmaf(e4m3_to_f32(l4 >> 24), (1.0f / 2048.0f), (float)h4[3]);
        *(float4*)&rg[eb] = o;
      }
      __hip_atomic_store(&sh.r.flags[pend & 3], pend + 1, __ATOMIC_RELEASE,
                         __HIP_MEMORY_SCOPE_WORKGROUP);
    }
  } else {
    // consumer: serial recurrence from f32 ring (R12-validated fast path)
    const int d = lane >> 4;
    const int cq = lane & 15;
    const bool d1 = (d & 1), d2 = (d & 2);
    const int pb = lane & 48;

    float4 hq;
    if (cc == 0) {
      hq = *(const float4*)(init_hidden + 4 * cq);
      float ss0 = row_sum16(hq.x * hq.x + hq.y * hq.y + hq.z * hq.z + hq.w * hq.w);
      float iv0 = 1.0f / fmaxf(sqrtf(ss0), 1e-12f);
      hq.x *= iv0; hq.y *= iv0; hq.z *= iv0; hq.w *= iv0;
    } else {
      hq = *(const float4*)(hstate + b * DS + 4 * cq);
    }
    float inv_prev = 1.0f;

    float* outp = out + ((size_t)b * S_ + s_base) * DS + 4 * cq;
    int fpre = -1;
    for (int s = 0; s < SC; ++s) {
      const int slot = s & 3;
      if (fpre < s + 1) {
        while (__hip_atomic_load(&sh.r.flags[slot], __ATOMIC_ACQUIRE,
                                 __HIP_MEMORY_SCOPE_WORKGROUP) < s + 1)
          __builtin_amdgcn_s_sleep(0);
      }
      fpre = __hip_atomic_load(&sh.r.flags[(s + 1) & 3], __ATOMIC_ACQUIRE,
                               __HIP_MEMORY_SCOPE_WORKGROUP);

      float hsel = d2 ? (d1 ? hq.w : hq.z) : (d1 ? hq.y : hq.x);
      float ax = 0.f, ay = 0.f, az = 0.f, aw = 0.f;
#pragma unroll
      for (int q = 0; q < 16; ++q) {
        float4 t4 = *(const float4*)&sh.r.ring[slot][256 * q + 4 * lane];
        float hb = __shfl(hsel, pb + q, 64);
        ax += hb * t4.x; ay += hb * t4.y;
        az += hb * t4.z; aw += hb * t4.w;
      }
      __hip_atomic_store(&sh.r.cons, s + 1, __ATOMIC_RELAXED,
                         __HIP_MEMORY_SCOPE_WORKGROUP);

      ax += __shfl_xor(ax, 16, 64); ax += __shfl_xor(ax, 32, 64);
      ay += __shfl_xor(ay, 16, 64); ay += __shfl_xor(ay, 32, 64);
      az += __shfl_xor(az, 16, 64); az += __shfl_xor(az, 32, 64);
      aw += __shfl_xor(aw, 16, 64); aw += __shfl_xor(aw, 32, 64);
      hq.x = fmaxf(ax * inv_prev, 0.f);
      hq.y = fmaxf(ay * inv_prev, 0.f);
      hq.z = fmaxf(az * inv_prev, 0.f);
      hq.w = fmaxf(aw * inv_prev, 0.f);
      float ss = row_sum16(hq.x * hq.x + hq.y * hq.y + hq.z * hq.z + hq.w * hq.w);
      float inv = 1.0f / fmaxf(sqrtf(ss), 1e-12f);
      if (d == 0) {
        float4 o;
        o.x = hq.x * inv; o.y = hq.y * inv; o.z = hq.z * inv; o.w = hq.w * inv;
        *(float4*)(outp + (size_t)s * DS) = o;
      }
      inv_prev = inv;
    }
    if (d == 0) {
      float4 o;   // carry NORMALIZED state across chunks
      o.x = hq.x * inv_prev; o.y = hq.y * inv_prev;
      o.z = hq.z * inv_prev; o.w = hq.w * inv_prev;
      *(float4*)(hstate + b * DS + 4 * cq) = o;
    }
  }
}

// ---------------------------------------------------------------------------
extern "C" void kernel_launch(void* const* d_in, const int* in_sizes, int n_in,
                              void* d_out, int out_size, void* d_ws, size_t ws_size,
                              hipStream_t stream) {
  const float* actions     = (const float*)d_in[0];
  const float* w0          = (const float*)d_in[1];
  const float* b0          = (const float*)d_in[2];
  const float* w1          = (const float*)d_in[3];
  const float* b1          = (const float*)d_in[4];
  const float* w2          = (const float*)d_in[5];
  const float* b2          = (const float*)d_in[6];
  const float* init_hidden = (const float*)d_in[7];
  float* out = (float*)d_out;

  // largest chunk whose workspace fits:
  // 2x transh (fp16) + 2x translo (u8) + 4x h1 split (f16) + 2x w2 split + hstate
  int SC = 2048;
  while (SC > 4) {
    size_t need = 2 * (size_t)SC * 32 * DS2 * 2
                + 2 * (size_t)SC * 32 * DS2
                + 4 * (size_t)SC * 32 * DH * 2
                + 2 * (size_t)DH * DS2 * 2
                + (size_t)B_ * DS * 4;
    if (need <= ws_size) break;
    SC >>= 1;
  }
  char* p = (char*)d_ws;
  _Float16* transh0 = (_Float16*)p;      p += (size_t)SC * 32 * DS2 * 2;
  _Float16* transh1 = (_Float16*)p;      p += (size_t)SC * 32 * DS2 * 2;
  _Float16* h1h0 = (_Float16*)p;         p += (size_t)SC * 32 * DH * 2;
  _Float16* h1l0 = (_Float16*)p;         p += (size_t)SC * 32 * DH * 2;
  _Float16* h1h1 = (_Float16*)p;         p += (size_t)SC * 32 * DH * 2;
  _Float16* h1l1 = (_Float16*)p;         p += (size_t)SC * 32 * DH * 2;
  _Float16* w2h  = (_Float16*)p;         p += (size_t)DH * DS2 * 2;
  _Float16* w2l  = (_Float16*)p;         p += (size_t)DH * DS2 * 2;
  unsigned char* translo0 = (unsigned char*)p;  p += (size_t)SC * 32 * DS2;
  unsigned char* translo1 = (unsigned char*)p;  p += (size_t)SC * 32 * DS2;
  float* hstate  = (float*)p;

  const int M = SC * 32;
  const int nch = S_ / SC;

  // prime: split w2 (once) and mlp for chunk 0 -> h1h0/h1l0
  hipLaunchKernelGGL(k_split, dim3(512), dim3(256), 0, stream, w2, w2h, w2l);
  hipLaunchKernelGGL(k_mlp01, dim3(M / 64), dim3(256), 0, stream,
                     actions, w0, b0, w1, b1, h1h0, h1l0, 0);
  // pipelined combined launches
  for (int c = 0; c <= nch; ++c) {
    hipLaunchKernelGGL(k_comb, dim3(256), dim3(256), 0, stream,
                       actions, w0, b0, w1, b1, w2h, w2l, b2, init_hidden,
                       transh0, transh1, translo0, translo1,
                       h1h0, h1l0, h1h1, h1l1, hstate, out,
                       c, SC, nch);
  }
}

// Round 17
// 1658.973 us; speedup vs baseline: 1.4608x; 1.4608x over previous
//
#include <hip/hip_runtime.h>

// Problem constants
#define B_ 32
#define S_ 2048
#define DA 32
#define DH 128
#define DS 64
#define DS2 4096

typedef _Float16 half8 __attribute__((ext_vector_type(8)));
typedef float f32x4 __attribute__((ext_vector_type(4)));

template <int CTRL>
__device__ __forceinline__ float dpp_add(float x) {
  int t = __builtin_amdgcn_update_dpp(0, __float_as_int(x), CTRL, 0xF, 0xF, true);
  return x + __int_as_float(t);
}
__device__ __forceinline__ float row_sum16(float x) {
  x = dpp_add<0xB1>(x);
  x = dpp_add<0x4E>(x);
  x = dpp_add<0x141>(x);
  x = dpp_add<0x140>(x);
  return x;
}

// async global->LDS DMA, 16 B per lane (dest = wave-uniform base + lane*16)
__device__ __forceinline__ void gl2lds16(const void* g, void* l) {
  __builtin_amdgcn_global_load_lds(
      (const __attribute__((address_space(1))) void*)g,
      (__attribute__((address_space(3))) void*)l, 16, 0, 0);
}

// ---------------------------------------------------------------------------
// R10==R12 at 0.74us/step across disjoint load engines; the shared piece is
// the consumer's 16x{ds_read_b128 + shfl} latency chain. This round: lane-j
// consumer -- h fully replicated in registers (1 ds_write + 16 BROADCAST
// b128 reads/step), matvec = 64 register FMAs (no shfl), T prefetched as
// 64 ds_read_b32 (2-way alias = free, h-independent -> overlaps compute).
// Producers/ring/flags = R12-validated verbatim. GEMM = R12 MFMA, f32 trans.
// ---------------------------------------------------------------------------
struct SharedRnn {
  float4 ring[6][16][64];   // 96 KB f32 T ring (layout = global, [i*64+j])
  float hlds[64];           // h replicate buffer
  int flags[6];
  int cons;
};
struct SharedGemm {
  _Float16 Ah[128 * 128];   // 32 KB  [m*128 + (k ^ ((m&7)<<3))]
  _Float16 Al[128 * 128];
  _Float16 Bh[128 * 128];   // 32 KB  [nloc*128 + (k ^ ((n&7)<<3))]
  _Float16 Bl[128 * 128];
};
struct SharedMlp {
  float a_t[DA][64];        // 8 KB
  float w0_l[DA][DH];       // 16 KB
  float h0t[DH][64];        // 32 KB
};
union SharedU {
  SharedRnn r;
  SharedGemm g;
  SharedMlp m;
};

// ---------------------------------------------------------------------------
// w2 split precompute (once): w2 [k][n] fp32 -> w2h/w2l [n][k^swz] fp16,
// lo scaled by 2^11 so it stays in fp16 normal range.
// ---------------------------------------------------------------------------
__global__ __launch_bounds__(256) void k_split(
    const float* __restrict__ w2, _Float16* __restrict__ w2h,
    _Float16* __restrict__ w2l)
{
  for (int e = blockIdx.x * 256 + threadIdx.x; e < DH * DS2;
       e += gridDim.x * 256) {
    int n = e >> 7, k = e & 127;
    float v = w2[(size_t)k * DS2 + n];
    _Float16 hi = (_Float16)v;
    _Float16 lo = (_Float16)((v - (float)hi) * 2048.0f);
    int kk = k ^ ((n & 7) << 3);
    w2h[(size_t)n * DH + kk] = hi;
    w2l[(size_t)n * DH + kk] = lo;
  }
}

// ---------------------------------------------------------------------------
// MLP tile (R0-validated 256-thread compute): 64 tokens; epilogue emits the
// fp16 hi/lo split of h1 in [m][k^swz] layout (k = feature).
// ---------------------------------------------------------------------------
__device__ __forceinline__ void mlp_tile(
    const float* __restrict__ actions, const float* __restrict__ w0,
    const float* __restrict__ b0, const float* __restrict__ w1,
    const float* __restrict__ b1, _Float16* __restrict__ h1h,
    _Float16* __restrict__ h1l, int s_base, int m0, SharedMlp& sm, int tid)
{
#pragma unroll
  for (int q = 0; q < 2; ++q) {
    int g = tid + 256 * q;
    int tok = g >> 3, kq = g & 7;
    int tl = m0 + tok;
    int b = tl & 31, s = s_base + (tl >> 5);
    float4 v = *(const float4*)(actions + ((size_t)b * S_ + s) * DA + 4 * kq);
    sm.a_t[4 * kq + 0][tok] = v.x; sm.a_t[4 * kq + 1][tok] = v.y;
    sm.a_t[4 * kq + 2][tok] = v.z; sm.a_t[4 * kq + 3][tok] = v.w;
  }
#pragma unroll
  for (int q = 0; q < 4; ++q) {
    int g = tid + 256 * q;
    ((float4*)&sm.w0_l[0][0])[g] = ((const float4*)w0)[g];
  }
  __syncthreads();

  const int tm = tid & 15;
  const int tn = tid >> 4;

  float acc[4][8];
#pragma unroll
  for (int mi = 0; mi < 4; ++mi)
#pragma unroll
    for (int ni = 0; ni < 8; ++ni) acc[mi][ni] = 0.f;

#pragma unroll 4
  for (int k = 0; k < DA; ++k) {
    float4 a4 = *(const float4*)&sm.a_t[k][4 * tm];
    float4 wa = *(const float4*)&sm.w0_l[k][8 * tn];
    float4 wb = *(const float4*)&sm.w0_l[k][8 * tn + 4];
    float av[4] = {a4.x, a4.y, a4.z, a4.w};
    float wv[8] = {wa.x, wa.y, wa.z, wa.w, wb.x, wb.y, wb.z, wb.w};
#pragma unroll
    for (int mi = 0; mi < 4; ++mi)
#pragma unroll
      for (int ni = 0; ni < 8; ++ni) acc[mi][ni] += av[mi] * wv[ni];
  }
  {
    float4 ba = *(const float4*)(b0 + 8 * tn);
    float4 bb = *(const float4*)(b0 + 8 * tn + 4);
    float bv[8] = {ba.x, ba.y, ba.z, ba.w, bb.x, bb.y, bb.z, bb.w};
#pragma unroll
    for (int mi = 0; mi < 4; ++mi)
#pragma unroll
      for (int ni = 0; ni < 8; ++ni)
        sm.h0t[8 * tn + ni][4 * tm + mi] = fmaxf(acc[mi][ni] + bv[ni], 0.f);
  }
  __syncthreads();

  float acc1[4][8];
#pragma unroll
  for (int mi = 0; mi < 4; ++mi)
#pragma unroll
    for (int ni = 0; ni < 8; ++ni) acc1[mi][ni] = 0.f;

#pragma unroll 4
  for (int k = 0; k < DH; ++k) {
    float4 h4 = *(const float4*)&sm.h0t[k][4 * tm];
    float4 wa = *(const float4*)(w1 + (size_t)k * DH + 8 * tn);
    float4 wb = *(const float4*)(w1 + (size_t)k * DH + 8 * tn + 4);
    float av[4] = {h4.x, h4.y, h4.z, h4.w};
    float wv[8] = {wa.x, wa.y, wa.z, wa.w, wb.x, wb.y, wb.z, wb.w};
#pragma unroll
    for (int mi = 0; mi < 4; ++mi)
#pragma unroll
      for (int ni = 0; ni < 8; ++ni) acc1[mi][ni] += av[mi] * wv[ni];
  }
  {
    float4 ba = *(const float4*)(b1 + 8 * tn);
    float4 bb = *(const float4*)(b1 + 8 * tn + 4);
    float bv[8] = {ba.x, ba.y, ba.z, ba.w, bb.x, bb.y, bb.z, bb.w};
#pragma unroll
    for (int mi = 0; mi < 4; ++mi) {
      const int m = m0 + 4 * tm + mi;
      half8 hv, lv;
#pragma unroll
      for (int ni = 0; ni < 8; ++ni) {
        float h = fmaxf(acc1[mi][ni] + bv[ni], 0.f);
        _Float16 hi = (_Float16)h;
        hv[ni] = hi;
        lv[ni] = (_Float16)((h - (float)hi) * 2048.0f);
      }
      const int off = m * DH + ((8 * tn) ^ ((m & 7) << 3));
      *(half8*)(h1h + off) = hv;
      *(half8*)(h1l + off) = lv;
    }
  }
}

// ---------------------------------------------------------------------------
// MFMA trans GEMM (R10/R12-validated): block owns n-strip; Bh/Bl pinned;
// per m-tile: stage Ah/Al -> MFMA -> f32 direct stores.
// C/D: col = lane&15, row = (lane>>4)*4 + reg (guide m89/m91 verified).
// ---------------------------------------------------------------------------
__device__ __forceinline__ void trans_loop(
    const _Float16* __restrict__ h1h, const _Float16* __restrict__ h1l,
    const _Float16* __restrict__ w2h, const _Float16* __restrict__ w2l,
    const float* __restrict__ b2, float* __restrict__ trans,
    int MT, int x, SharedGemm& sg, int tid)
{
  const int w  = tid >> 6;
  const int lw = tid & 63;
  const int strip = x / 7;            // 0..31
  const int idx   = x % 7;
  const int n0 = strip * 128;

  // per-wave linear 8 KB staging helper (32 KB array / 4 waves)
  auto stage32k = [&](const _Float16* src, _Float16* dst) {
    const _Float16* s = src + w * 4096 + lw * 8;
    _Float16* d = dst + w * 4096;
#pragma unroll
    for (int i = 0; i < 8; ++i)
      gl2lds16(s + i * 512, d + i * 512);
  };

  // pin B strip (w2 splits are [n][k^swz], contiguous per strip)
  stage32k(w2h + (size_t)n0 * DH, sg.Bh);
  stage32k(w2l + (size_t)n0 * DH, sg.Bl);

  const int fr = lw & 15;             // frag row/col index
  const int kg = lw >> 4;             // 0..3 k-group
  const int wr = w >> 1, wc = w & 1;  // wave quadrant

  float b2v[4];
#pragma unroll
  for (int fn = 0; fn < 4; ++fn)
    b2v[fn] = b2[n0 + wc * 64 + fn * 16 + fr];

  const f32x4 fz = {0.f, 0.f, 0.f, 0.f};

  for (int mt = idx; mt < MT; mt += 7) {
    const int m0 = mt * 128;
    stage32k(h1h + (size_t)m0 * DH, sg.Ah);
    stage32k(h1l + (size_t)m0 * DH, sg.Al);
    asm volatile("s_waitcnt vmcnt(0)" ::: "memory");
    __syncthreads();

    f32x4 ahh[4][4], axx[4][4], all_[4][4];
#pragma unroll
    for (int fm = 0; fm < 4; ++fm)
#pragma unroll
      for (int fn = 0; fn < 4; ++fn) {
        ahh[fm][fn] = fz;
        axx[fm][fn] = fz;
        all_[fm][fn] = fz;
      }

#pragma unroll
    for (int kc = 0; kc < 4; ++kc) {
      const int k0 = kc * 32 + kg * 8;
      half8 bh[4], bl[4];
#pragma unroll
      for (int fn = 0; fn < 4; ++fn) {
        const int n = wc * 64 + fn * 16 + fr;
        const int off = n * DH + (k0 ^ ((n & 7) << 3));
        bh[fn] = *(const half8*)&sg.Bh[off];
        bl[fn] = *(const half8*)&sg.Bl[off];
      }
#pragma unroll
      for (int fm = 0; fm < 4; ++fm) {
        const int m = wr * 64 + fm * 16 + fr;
        const int off = m * DH + (k0 ^ ((m & 7) << 3));
        half8 ah = *(const half8*)&sg.Ah[off];
        half8 al = *(const half8*)&sg.Al[off];
#pragma unroll
        for (int fn = 0; fn < 4; ++fn) {
          ahh[fm][fn] = __builtin_amdgcn_mfma_f32_16x16x32_f16(
              ah, bh[fn], ahh[fm][fn], 0, 0, 0);
          axx[fm][fn] = __builtin_amdgcn_mfma_f32_16x16x32_f16(
              ah, bl[fn], axx[fm][fn], 0, 0, 0);
          axx[fm][fn] = __builtin_amdgcn_mfma_f32_16x16x32_f16(
              al, bh[fn], axx[fm][fn], 0, 0, 0);
          all_[fm][fn] = __builtin_amdgcn_mfma_f32_16x16x32_f16(
              al, bl[fn], all_[fm][fn], 0, 0, 0);
        }
      }
    }
    __syncthreads();   // all LDS reads done before next tile's staging

    // epilogue: C/D layout col = lane&15, row = (lane>>4)*4 + reg
#pragma unroll
    for (int fm = 0; fm < 4; ++fm) {
#pragma unroll
      for (int fn = 0; fn < 4; ++fn) {
        const int col = n0 + wc * 64 + fn * 16 + fr;
        float* dst = trans +
            (size_t)(m0 + wr * 64 + fm * 16 + kg * 4) * DS2 + col;
#pragma unroll
        for (int r = 0; r < 4; ++r) {
          float v = ahh[fm][fn][r] + axx[fm][fn][r] * (1.0f / 2048.0f) +
                    all_[fm][fn][r] * (1.0f / 4194304.0f) + b2v[fn];
          dst[(size_t)r * DS2] = v;
        }
      }
    }
  }
}

// ---------------------------------------------------------------------------
// Standalone MLP kernel (chunk 0 priming)
// ---------------------------------------------------------------------------
__global__ __launch_bounds__(256) void k_mlp01(
    const float* __restrict__ actions, const float* __restrict__ w0,
    const float* __restrict__ b0, const float* __restrict__ w1,
    const float* __restrict__ b1, _Float16* __restrict__ h1h,
    _Float16* __restrict__ h1l, int s_base)
{
  __shared__ SharedMlp sm;
  mlp_tile(actions, w0, b0, w1, b1, h1h, h1l, s_base, blockIdx.x * 64, sm,
           threadIdx.x);
}

// ---------------------------------------------------------------------------
// Combined pipelined kernel, launch index c = 0..nch, grid 256 x 256 thr:
//  blocks 0..31  : rnn for chunk c-1 (if c>0) -- R12-validated producers
//                  (waves 1..3, stride 3, 6-slot ring) + lane-j register
//                  consumer (wave 0): no shfl in the matvec, h replicated
//                  via broadcast LDS reads, T prefetched into registers.
//  blocks 32..255: MFMA trans tiles for chunk c (if c<nch), then mlp c+1.
// ---------------------------------------------------------------------------
__global__ __launch_bounds__(256, 1) void k_comb(
    const float* __restrict__ actions, const float* __restrict__ w0,
    const float* __restrict__ b0, const float* __restrict__ w1,
    const float* __restrict__ b1, const _Float16* __restrict__ w2h,
    const _Float16* __restrict__ w2l, const float* __restrict__ b2,
    const float* __restrict__ init_hidden,
    float* __restrict__ trans0, float* __restrict__ trans1,
    _Float16* __restrict__ h1h0, _Float16* __restrict__ h1l0,
    _Float16* __restrict__ h1h1, _Float16* __restrict__ h1l1,
    float* __restrict__ hstate, float* __restrict__ out,
    int c, int SC, int nch)
{
  __shared__ SharedU sh;
  const int tid = threadIdx.x;
  const int M = SC * 32;

  if (blockIdx.x >= 32) {
    // -------------------- GEMM blocks (224) --------------------
    const int x = blockIdx.x - 32;
    if (c < nch) {
      const _Float16* h1h = (c & 1) ? h1h1 : h1h0;
      const _Float16* h1l = (c & 1) ? h1l1 : h1l0;
      float* trans = (c & 1) ? trans1 : trans0;
      trans_loop(h1h, h1l, w2h, w2l, b2, trans, M / 128, x, sh.g, tid);
      if (c + 1 < nch) {
        __syncthreads();
        _Float16* hh = ((c + 1) & 1) ? h1h1 : h1h0;
        _Float16* hl = ((c + 1) & 1) ? h1l1 : h1l0;
        for (int j = x; j < M / 64; j += 224) {
          mlp_tile(actions, w0, b0, w1, b1, hh, hl, (c + 1) * SC, j * 64,
                   sh.m, tid);
          __syncthreads();
        }
      }
    }
    return;
  }

  // -------------------- RNN blocks (chunk c-1) ----------------------------
  if (c == 0) return;
  const int cc = c - 1;               // rnn chunk index
  const float* trans = (cc & 1) ? trans1 : trans0;
  const int s_base = cc * SC;
  const int wv = tid >> 6;            // 0..3
  const int lane = tid & 63;
  const int b = blockIdx.x;

  if (tid < 6) sh.r.flags[tid] = 0;
  if (tid == 6) sh.r.cons = 0;
  __syncthreads();

  const float* base = trans + (size_t)b * DS2;

  if (wv > 0) {
    // producer: steps s ≡ wv-1 (mod 3)  [R12-validated protocol]
    const int p = wv - 1;
    int prev = -1;
    for (int s = p; s < SC; s += 3) {
      while (s - __hip_atomic_load(&sh.r.cons, __ATOMIC_RELAXED,
                                   __HIP_MEMORY_SCOPE_WORKGROUP) > 5)
        __builtin_amdgcn_s_sleep(2);
      const int slot = s % 6;
      const float* g = base + (size_t)s * (32 * DS2) + 4 * lane;
      float* l = (float*)&sh.r.ring[slot][0][0];
#pragma unroll
      for (int q = 0; q < 16; ++q)
        gl2lds16(g + q * 256, l + q * 256);
      if (prev >= 0) {
        asm volatile("s_waitcnt vmcnt(16)" ::: "memory");
        __hip_atomic_store(&sh.r.flags[prev % 6], prev + 1, __ATOMIC_RELAXED,
                           __HIP_MEMORY_SCOPE_WORKGROUP);
      }
      prev = s;
    }
    if (prev >= 0) {
      asm volatile("s_waitcnt vmcnt(0)" ::: "memory");
      __hip_atomic_store(&sh.r.flags[prev % 6], prev + 1, __ATOMIC_RELAXED,
                         __HIP_MEMORY_SCOPE_WORKGROUP);
    }
  } else {
    // ---------------- lane-j register consumer --------------------------
    float h[64];        // replicated raw previous h
    float TA[64], TB[64];
    float inv_prev = 1.0f;
    float hj;           // this lane's raw h component

    if (cc == 0) {
      float v = init_hidden[lane];
      float t0 = v * v;
      t0 = row_sum16(t0);
      t0 += __shfl_xor(t0, 16, 64);
      t0 += __shfl_xor(t0, 32, 64);
      float iv0 = 1.0f / fmaxf(sqrtf(t0), 1e-12f);
      hj = v * iv0;                    // normalized init (matches reference)
    } else {
      hj = hstate[b * DS + lane];      // normalized carry
    }
    sh.r.hlds[lane] = hj;
#pragma unroll
    for (int g = 0; g < 16; ++g) {
      float4 v4 = *(const float4*)&sh.r.hlds[4 * g];   // broadcast read
      h[4 * g] = v4.x; h[4 * g + 1] = v4.y;
      h[4 * g + 2] = v4.z; h[4 * g + 3] = v4.w;
    }

    float* outp = out + ((size_t)b * S_ + s_base) * DS + lane;
    const float* ringf = (const float*)&sh.r.ring[0][0][0];

    // prime: T(0) into TA
    while (__hip_atomic_load(&sh.r.flags[0], __ATOMIC_ACQUIRE,
                             __HIP_MEMORY_SCOPE_WORKGROUP) < 1)
      __builtin_amdgcn_s_sleep(0);
#pragma unroll
    for (int i = 0; i < 64; ++i) TA[i] = ringf[i * 64 + lane];

    auto step_body = [&](float (&Tc)[64], float (&Tn)[64], int s) {
      // prefetch T(s+1) into Tn (independent of h -> overlaps compute)
      if (s + 1 < SC) {
        const int sl = (s + 1) % 6;
        while (__hip_atomic_load(&sh.r.flags[sl], __ATOMIC_ACQUIRE,
                                 __HIP_MEMORY_SCOPE_WORKGROUP) < s + 2)
          __builtin_amdgcn_s_sleep(0);
        const float* rp = ringf + sl * 4096;
#pragma unroll
        for (int i = 0; i < 64; ++i) Tn[i] = rp[i * 64 + lane];
      }
      // matvec: pure register FMAs, 4 chains
      float a0 = 0.f, a1 = 0.f, a2 = 0.f, a3 = 0.f;
#pragma unroll
      for (int i = 0; i < 64; i += 4) {
        a0 = fmaf(h[i], Tc[i], a0);
        a1 = fmaf(h[i + 1], Tc[i + 1], a1);
        a2 = fmaf(h[i + 2], Tc[i + 2], a2);
        a3 = fmaf(h[i + 3], Tc[i + 3], a3);
      }
      __hip_atomic_store(&sh.r.cons, s + 1, __ATOMIC_RELAXED,
                         __HIP_MEMORY_SCOPE_WORKGROUP);
      float ax = (a0 + a1) + (a2 + a3);
      hj = fmaxf(ax * inv_prev, 0.f);
      float t = hj * hj;
      t = row_sum16(t);
      t += __shfl_xor(t, 16, 64);
      t += __shfl_xor(t, 32, 64);
      float inv = 1.0f / fmaxf(sqrtf(t), 1e-12f);
      outp[(size_t)s * DS] = hj * inv;
      // replicate raw hj to all lanes (write + broadcast reads)
      sh.r.hlds[lane] = hj;
#pragma unroll
      for (int g = 0; g < 16; ++g) {
        float4 v4 = *(const float4*)&sh.r.hlds[4 * g];
        h[4 * g] = v4.x; h[4 * g + 1] = v4.y;
        h[4 * g + 2] = v4.z; h[4 * g + 3] = v4.w;
      }
      inv_prev = inv;
    };

    for (int s = 0; s < SC; s += 2) {   // SC even
      step_body(TA, TB, s);
      step_body(TB, TA, s + 1);
    }

    // carry NORMALIZED state across chunks
    hstate[b * DS + lane] = hj * inv_prev;
  }
}

// ---------------------------------------------------------------------------
extern "C" void kernel_launch(void* const* d_in, const int* in_sizes, int n_in,
                              void* d_out, int out_size, void* d_ws, size_t ws_size,
                              hipStream_t stream) {
  const float* actions     = (const float*)d_in[0];
  const float* w0          = (const float*)d_in[1];
  const float* b0          = (const float*)d_in[2];
  const float* w1          = (const float*)d_in[3];
  const float* b1          = (const float*)d_in[4];
  const float* w2          = (const float*)d_in[5];
  const float* b2          = (const float*)d_in[6];
  const float* init_hidden = (const float*)d_in[7];
  float* out = (float*)d_out;

  // largest chunk whose workspace fits:
  // 2x trans (f32) + 4x h1 split (f16) + 2x w2 split (f16) + hstate
  int SC = 2048;
  while (SC > 4) {
    size_t need = 2 * (size_t)SC * 32 * DS2 * 4
                + 4 * (size_t)SC * 32 * DH * 2
                + 2 * (size_t)DH * DS2 * 2
                + (size_t)B_ * DS * 4;
    if (need <= ws_size) break;
    SC >>= 1;
  }
  char* p = (char*)d_ws;
  float* trans0 = (float*)p;        p += (size_t)SC * 32 * DS2 * 4;
  float* trans1 = (float*)p;        p += (size_t)SC * 32 * DS2 * 4;
  _Float16* h1h0 = (_Float16*)p;    p += (size_t)SC * 32 * DH * 2;
  _Float16* h1l0 = (_Float16*)p;    p += (size_t)SC * 32 * DH * 2;
  _Float16* h1h1 = (_Float16*)p;    p += (size_t)SC * 32 * DH * 2;
  _Float16* h1l1 = (_Float16*)p;    p += (size_t)SC * 32 * DH * 2;
  _Float16* w2h  = (_Float16*)p;    p += (size_t)DH * DS2 * 2;
  _Float16* w2l  = (_Float16*)p;    p += (size_t)DH * DS2 * 2;
  float* hstate  = (float*)p;

  const int M = SC * 32;
  const int nch = S_ / SC;

  // prime: split w2 (once) and mlp for chunk 0 -> h1h0/h1l0
  hipLaunchKernelGGL(k_split, dim3(512), dim3(256), 0, stream, w2, w2h, w2l);
  hipLaunchKernelGGL(k_mlp01, dim3(M / 64), dim3(256), 0, stream,
                     actions, w0, b0, w1, b1, h1h0, h1l0, 0);
  // pipelined combined launches
  for (int c = 0; c <= nch; ++c) {
    hipLaunchKernelGGL(k_comb, dim3(256), dim3(256), 0, stream,
                       actions, w0, b0, w1, b1, w2h, w2l, b2, init_hidden,
                       trans0, trans1, h1h0, h1l0, h1h1, h1l1, hstate, out,
                       c, SC, nch);
  }
}